// Round 2
// baseline (4665.590 us; speedup 1.0000x reference)
//
#include <hip/hip_runtime.h>
#include <hip/hip_bf16.h>

#define B_ 256
#define T_ 512
#define E_ 128
#define H_ 256

typedef __attribute__((ext_vector_type(8))) short short8;
typedef __attribute__((ext_vector_type(4))) float f32x4;
typedef unsigned short u16;

#define MFMA_BF16(a, b, c) __builtin_amdgcn_mfma_f32_16x16x32_bf16((a), (b), (c), 0, 0, 0)

__device__ __forceinline__ u16 f2bf(float f) {
    union { float f; unsigned int u; } v; v.f = f;
    unsigned int u = v.u;
    unsigned int r = (u + 0x7fffu + ((u >> 16) & 1u)) >> 16;  // RNE
    return (u16)r;
}
__device__ __forceinline__ float bflo(unsigned int u) {
    union { unsigned int u; float f; } v; v.u = u << 16; return v.f;
}
__device__ __forceinline__ float bfhi(unsigned int u) {
    union { unsigned int u; float f; } v; v.u = u & 0xffff0000u; return v.f;
}
__device__ __forceinline__ f32x4 up2(uint2 p) {
    f32x4 r; r[0] = bflo(p.x); r[1] = bfhi(p.x); r[2] = bflo(p.y); r[3] = bfhi(p.y); return r;
}
__device__ __forceinline__ uint2 pk4(float a, float b, float c, float d) {
    uint2 o;
    o.x = (unsigned)f2bf(a) | ((unsigned)f2bf(b) << 16);
    o.y = (unsigned)f2bf(c) | ((unsigned)f2bf(d) << 16);
    return o;
}
__device__ __forceinline__ float sigm(float x) { return 1.f / (1.f + __expf(-x)); }

// ---------------- fp32 -> bf16 weight conversion ----------------
__global__ void f32_to_bf16_kernel(const float* __restrict__ src, u16* __restrict__ dst, int n2) {
    int i = blockIdx.x * blockDim.x + threadIdx.x;
    if (i < n2) {
        float2 v = ((const float2*)src)[i];
        ushort2 o; o.x = f2bf(v.x); o.y = f2bf(v.y);
        ((ushort2*)dst)[i] = o;
    }
}

// ================= PATH A: xp precompute + register-resident recurrence =================

// xp layout (bf16): [dir][t][btile16][ntile48][lane64][rr4]
//   value for (t, b = btile*16 + quad*4 + rr, ncol = ntile*16 + nl), lane = quad*16+nl.
//   r/z ntiles (<32) carry b_ih+b_hh folded in; n-gate ntiles carry b_ih only.
#define XP_T_STRIDE_U2 49152   // 16*48*64 uint2 per t

__launch_bounds__(512, 1)
__global__ void xp_gemm_kernel(const int* __restrict__ x, const float* __restrict__ emb,
                               const u16* __restrict__ wih,
                               const float* __restrict__ bih_f, const float* __restrict__ bhh_f,
                               const float* __restrict__ bih_b, const float* __restrict__ bhh_b,
                               u16* __restrict__ xp) {
    const int dir    = blockIdx.x >> 11;     // 2048 m-blocks per dir
    const int mblock = blockIdx.x & 2047;
    const int t      = mblock >> 2;          // 64 rows per block, 256 rows per t
    const int b0     = (mblock & 3) << 6;
    const int tid  = threadIdx.x;
    const int wv   = tid >> 6;
    const int lane = tid & 63;
    const int nl   = lane & 15;
    const int quad = lane >> 4;

    __shared__ u16 A[64][136];   // +8 pad: 2-way-free bank pattern on b128 reads

    const u16*   wih_d = wih + (size_t)dir * (768 * 128);
    const float* bih   = dir ? bih_b : bih_f;
    const float* bhh   = dir ? bhh_b : bhh_f;

    // B fragments: wave wv owns ntiles wv*6 .. wv*6+5 (pure reg-resident, from L2)
    short8 bfrag[6][4];
#pragma unroll
    for (int j = 0; j < 6; j++) {
        int nt = wv * 6 + j;
        const u16* p = wih_d + (size_t)(nt * 16 + nl) * 128 + quad * 8;
#pragma unroll
        for (int kt = 0; kt < 4; kt++) bfrag[j][kt] = *(const short8*)(p + kt * 32);
    }

    // stage A: embedding gather + bf16 convert, 64 rows x 128 cols
#pragma unroll
    for (int i = 0; i < 4; i++) {
        int idx = tid + i * 512;            // 2048 float4 chunks
        int r = idx >> 5, c = idx & 31;
        int tok = x[(b0 + r) * T_ + t];
        float4 v = *(const float4*)(emb + (size_t)tok * E_ + c * 4);
        uint2 o = pk4(v.x, v.y, v.z, v.w);
        *(uint2*)&A[r][c * 4] = o;
    }
    __syncthreads();

    f32x4 acc[6][4];
#pragma unroll
    for (int j = 0; j < 6; j++)
#pragma unroll
        for (int mi = 0; mi < 4; mi++) acc[j][mi] = (f32x4){0, 0, 0, 0};

#pragma unroll
    for (int kt = 0; kt < 4; kt++) {
        short8 a[4];
#pragma unroll
        for (int mi = 0; mi < 4; mi++)
            a[mi] = *(const short8*)&A[mi * 16 + nl][quad * 8 + kt * 32];
#pragma unroll
        for (int j = 0; j < 6; j++)
#pragma unroll
            for (int mi = 0; mi < 4; mi++)
                acc[j][mi] = MFMA_BF16(a[mi], bfrag[j][kt], acc[j][mi]);
    }

    // epilogue: fold biases, pack bf16, store in recurrence-ready layout
#pragma unroll
    for (int j = 0; j < 6; j++) {
        int nt = wv * 6 + j;
        int ncol = nt * 16 + nl;
        int gate = nt >> 4;
        float bias = bih[ncol] + (gate < 2 ? bhh[ncol] : 0.f);
#pragma unroll
        for (int mi = 0; mi < 4; mi++) {
            int btile = ((mblock & 3) << 2) + mi;
            f32x4 v = acc[j][mi];
            uint2 o = pk4(v[0] + bias, v[1] + bias, v[2] + bias, v[3] + bias);
            size_t base = ((((size_t)(dir * 512 + t) * 16 + btile) * 48 + nt) * 64
                           + (quad * 16 + nl));
            ((uint2*)xp)[base] = o;
        }
    }
}

// Recurrence: 32 blocks (dir x 16 batch tiles), 512 thr = 8 waves.
// Wave wv owns units u0=wv*32+nl, u1=u0+16. w_hh fragments: 5 sets in VGPRs,
// the 6th (n-gate, u1) in LDS to stay under 256 VGPR @ 2 waves/SIMD.
__launch_bounds__(512, 1)
__global__ void gru_xp_kernel(const u16* __restrict__ xp, const u16* __restrict__ whh,
                              const float* __restrict__ bhh_f, const float* __restrict__ bhh_b,
                              const int* __restrict__ lengths,
                              float* __restrict__ hcat) {
    const int dir    = blockIdx.x >> 4;
    const int btile  = blockIdx.x & 15;
    const int b_base = btile << 4;
    const int wv     = threadIdx.x >> 6;
    const int lane   = threadIdx.x & 63;
    const int nl     = lane & 15;
    const int quad   = lane >> 4;

    __shared__ u16 hbuf[2][16][264];   // double-buffered h mirror (bf16)
    __shared__ u16 wn[128][264];       // w_hh rows 512+u1 for all waves

    const u16*   whh_d = whh + (size_t)dir * (768 * 256);
    const float* bhh   = dir ? bhh_b : bhh_f;

    const int u0 = wv * 32 + nl;
    const int u1 = u0 + 16;

    // stage wn: row r -> w_hh row 512 + (r>>4)*32 + 16 + (r&15)
    {
        int r = threadIdx.x >> 2, seg = threadIdx.x & 3;
        int n = 512 + ((r >> 4) << 5) + 16 + (r & 15);
        const u16* src = whh_d + (size_t)n * 256 + seg * 64;
#pragma unroll
        for (int i = 0; i < 8; i++)
            *(short8*)&wn[r][seg * 64 + i * 8] = *(const short8*)(src + i * 8);
    }
    // zero h buffers
    for (int i = threadIdx.x; i < 2 * 16 * 264; i += 512) (&hbuf[0][0][0])[i] = 0;

    // register-resident w_hh fragments: (r,u0),(r,u1),(z,u0),(z,u1),(n,u0)
    short8 w[5][8];
    {
        int nrow[5] = {u0, u1, 256 + u0, 256 + u1, 512 + u0};
#pragma unroll
        for (int gh = 0; gh < 5; gh++) {
            const u16* p = whh_d + (size_t)nrow[gh] * 256 + quad * 8;
#pragma unroll
            for (int kt = 0; kt < 8; kt++) w[gh][kt] = *(const short8*)(p + kt * 32);
        }
    }

    float bias_nh0 = bhh[512 + u0];
    float bias_nh1 = bhh[512 + u1];

    int len[4];
#pragma unroll
    for (int rr = 0; rr < 4; rr++) len[rr] = lengths[b_base + quad * 4 + rr];

    float hreg[2][4];
#pragma unroll
    for (int hh = 0; hh < 2; hh++)
#pragma unroll
        for (int rr = 0; rr < 4; rr++) hreg[hh][rr] = 0.f;

    // xp pointers: one per gate (hh offset = +64 uint2 = imm 512B)
    const int t0 = dir ? (T_ - 1) : 0;
    const long dstep = dir ? -(long)XP_T_STRIDE_U2 : (long)XP_T_STRIDE_U2;
    const uint2* pg[3];
#pragma unroll
    for (int g = 0; g < 3; g++) {
        size_t idx = ((((size_t)(dir * 512 + t0) * 16 + btile) * 48 + (g * 16 + wv * 2)) * 64
                      + (quad * 16 + nl));
        pg[g] = (const uint2*)xp + idx;
    }

    // prefetch step 0
    uint2 pf[3][2];
#pragma unroll
    for (int g = 0; g < 3; g++) { pf[g][0] = pg[g][0]; pf[g][1] = pg[g][64]; }

    __syncthreads();

    for (int s = 0; s < T_; s++) {
        const int t = dir ? (T_ - 1 - s) : s;
        const int cur = s & 1, nxt = cur ^ 1;

        // consume prefetched xp
        f32x4 accr[2], accz[2], accn[2], xpn[2];
#pragma unroll
        for (int hh = 0; hh < 2; hh++) {
            accr[hh] = up2(pf[0][hh]);
            accz[hh] = up2(pf[1][hh]);
            xpn[hh]  = up2(pf[2][hh]);
        }
        accn[0] = (f32x4){bias_nh0, bias_nh0, bias_nh0, bias_nh0};
        accn[1] = (f32x4){bias_nh1, bias_nh1, bias_nh1, bias_nh1};

        // prefetch next step (t=+-1 past the end reads valid-but-unused ws bytes)
#pragma unroll
        for (int g = 0; g < 3; g++) {
            pg[g] += dstep;
            pf[g][0] = pg[g][0];
            pf[g][1] = pg[g][64];
        }

        // recurrent matmul: A = h tile (LDS), B = reg/LDS-resident w_hh
#pragma unroll
        for (int kt = 0; kt < 8; kt++) {
            short8 a = *(const short8*)&hbuf[cur][nl][quad * 8 + kt * 32];
            accr[0] = MFMA_BF16(a, w[0][kt], accr[0]);
            accr[1] = MFMA_BF16(a, w[1][kt], accr[1]);
            accz[0] = MFMA_BF16(a, w[2][kt], accz[0]);
            accz[1] = MFMA_BF16(a, w[3][kt], accz[1]);
            accn[0] = MFMA_BF16(a, w[4][kt], accn[0]);
            short8 bn = *(const short8*)&wn[wv * 16 + nl][quad * 8 + kt * 32];
            accn[1] = MFMA_BF16(a, bn, accn[1]);
        }

        // gates + masked update
#pragma unroll
        for (int hh = 0; hh < 2; hh++) {
            int uu = hh ? u1 : u0;
#pragma unroll
            for (int rr = 0; rr < 4; rr++) {
                float r = sigm(accr[hh][rr]);
                float z = sigm(accz[hh][rr]);
                float npre = xpn[hh][rr] + r * accn[hh][rr];
                float nn = 1.f - 2.f / (1.f + __expf(2.f * npre));
                float hn = nn + z * (hreg[hh][rr] - nn);
                if (t < len[rr]) hreg[hh][rr] = hn;
                hbuf[nxt][quad * 4 + rr][uu] = f2bf(hreg[hh][rr]);
            }
        }
        __syncthreads();
    }

#pragma unroll
    for (int rr = 0; rr < 4; rr++) {
        hcat[(size_t)(b_base + quad * 4 + rr) * 512 + dir * 256 + u0] = hreg[0][rr];
        hcat[(size_t)(b_base + quad * 4 + rr) * 512 + dir * 256 + u1] = hreg[1][rr];
    }
}

// ================= PATH B (fallback, R0-proven): streamed weights =================

__global__ void gather_emb_kernel(const int* __restrict__ x, const float* __restrict__ emb,
                                  u16* __restrict__ out) {
    int gid = blockIdx.x * 256 + threadIdx.x;
    int pc  = gid & 63;
    int row = gid >> 6;
    int t = row >> 8;
    int b = row & 255;
    int tok = x[b * T_ + t];
    float2 v = *(const float2*)(emb + (size_t)tok * E_ + pc * 2);
    ushort2 o; o.x = f2bf(v.x); o.y = f2bf(v.y);
    *(ushort2*)(out + (size_t)row * E_ + pc * 2) = o;
}

__launch_bounds__(512, 1)
__global__ void gru_stream_kernel(const u16* __restrict__ emb, const u16* __restrict__ wih,
                                  const u16* __restrict__ whh,
                                  const float* __restrict__ bih_f, const float* __restrict__ bhh_f,
                                  const float* __restrict__ bih_b, const float* __restrict__ bhh_b,
                                  const int* __restrict__ lengths,
                                  float* __restrict__ hcat) {
    const int dir    = blockIdx.x >> 4;
    const int b_base = (blockIdx.x & 15) << 4;
    const int wv     = threadIdx.x >> 6;
    const int lane   = threadIdx.x & 63;
    const int nl     = lane & 15;
    const int quad   = lane >> 4;

    __shared__ u16 hbuf[2][16][264];

    const u16* wih_d = wih + (size_t)dir * (768 * 128);
    const u16* whh_d = whh + (size_t)dir * (768 * 256);
    const float* bih = dir ? bih_b : bih_f;
    const float* bhh = dir ? bhh_b : bhh_f;

    int u[2]; u[0] = wv * 32 + nl; u[1] = u[0] + 16;

    float bias_r[2], bias_z[2], bias_nx[2], bias_nh[2];
    const u16 *pih_r[2], *pih_z[2], *pih_n[2], *phh_r[2], *phh_z[2], *phh_n[2];
#pragma unroll
    for (int hh = 0; hh < 2; hh++) {
        int uu = u[hh];
        bias_r[hh]  = bih[uu]       + bhh[uu];
        bias_z[hh]  = bih[256 + uu] + bhh[256 + uu];
        bias_nx[hh] = bih[512 + uu];
        bias_nh[hh] = bhh[512 + uu];
        pih_r[hh] = wih_d + (size_t)uu * 128 + quad * 8;
        pih_z[hh] = wih_d + (size_t)(256 + uu) * 128 + quad * 8;
        pih_n[hh] = wih_d + (size_t)(512 + uu) * 128 + quad * 8;
        phh_r[hh] = whh_d + (size_t)uu * 256 + quad * 8;
        phh_z[hh] = whh_d + (size_t)(256 + uu) * 256 + quad * 8;
        phh_n[hh] = whh_d + (size_t)(512 + uu) * 256 + quad * 8;
    }

    int len[4];
#pragma unroll
    for (int rr = 0; rr < 4; rr++) len[rr] = lengths[b_base + quad * 4 + rr];

    float hreg[2][4];
#pragma unroll
    for (int hh = 0; hh < 2; hh++)
#pragma unroll
        for (int rr = 0; rr < 4; rr++) hreg[hh][rr] = 0.f;

    u16* hz = &hbuf[0][0][0];
    for (int i = threadIdx.x; i < 2 * 16 * 264; i += 512) hz[i] = 0;
    __syncthreads();

    for (int s = 0; s < T_; s++) {
        const int t = dir ? (T_ - 1 - s) : s;
        const int cur = s & 1, nxt = cur ^ 1;

        f32x4 ar[2]  = {{0,0,0,0},{0,0,0,0}};
        f32x4 az[2]  = {{0,0,0,0},{0,0,0,0}};
        f32x4 anx[2] = {{0,0,0,0},{0,0,0,0}};
        f32x4 anh[2] = {{0,0,0,0},{0,0,0,0}};

        const u16* erow = emb + ((size_t)t * B_ + b_base + nl) * E_ + quad * 8;
#pragma unroll
        for (int kt = 0; kt < 4; kt++) {
            short8 a = *(const short8*)(erow + kt * 32);
#pragma unroll
            for (int hh = 0; hh < 2; hh++) {
                short8 br = *(const short8*)(pih_r[hh] + kt * 32);
                short8 bz = *(const short8*)(pih_z[hh] + kt * 32);
                short8 bn = *(const short8*)(pih_n[hh] + kt * 32);
                ar[hh]  = MFMA_BF16(a, br, ar[hh]);
                az[hh]  = MFMA_BF16(a, bz, az[hh]);
                anx[hh] = MFMA_BF16(a, bn, anx[hh]);
            }
        }
        const u16* hrow = &hbuf[cur][nl][quad * 8];
#pragma unroll
        for (int kt = 0; kt < 8; kt++) {
            short8 a = *(const short8*)(hrow + kt * 32);
#pragma unroll
            for (int hh = 0; hh < 2; hh++) {
                short8 br = *(const short8*)(phh_r[hh] + kt * 32);
                short8 bz = *(const short8*)(phh_z[hh] + kt * 32);
                short8 bn = *(const short8*)(phh_n[hh] + kt * 32);
                ar[hh]  = MFMA_BF16(a, br, ar[hh]);
                az[hh]  = MFMA_BF16(a, bz, az[hh]);
                anh[hh] = MFMA_BF16(a, bn, anh[hh]);
            }
        }

#pragma unroll
        for (int hh = 0; hh < 2; hh++) {
#pragma unroll
            for (int rr = 0; rr < 4; rr++) {
                float r = sigm(ar[hh][rr] + bias_r[hh]);
                float z = sigm(az[hh][rr] + bias_z[hh]);
                float npre = anx[hh][rr] + bias_nx[hh] + r * (anh[hh][rr] + bias_nh[hh]);
                float nn = 1.f - 2.f / (1.f + __expf(2.f * npre));
                float hn = (1.f - z) * nn + z * hreg[hh][rr];
                if (t < len[rr]) hreg[hh][rr] = hn;
                hbuf[nxt][quad * 4 + rr][u[hh]] = f2bf(hreg[hh][rr]);
            }
        }
        __syncthreads();
    }

#pragma unroll
    for (int hh = 0; hh < 2; hh++)
#pragma unroll
        for (int rr = 0; rr < 4; rr++)
            hcat[(size_t)(b_base + quad * 4 + rr) * 512 + dir * 256 + u[hh]] = hreg[hh][rr];
}

// ---------------- FC head + row L2-normalize (shared) ----------------
__global__ void fc_head_kernel(const float* __restrict__ hcat,
                               const float* __restrict__ fc1w, const float* __restrict__ fc1b,
                               const float* __restrict__ fc2w, const float* __restrict__ fc2b,
                               float* __restrict__ out) {
    int row = blockIdx.x;
    int tid = threadIdx.x;  // 128
    __shared__ float hrow[512];
    __shared__ float hid[128];

    float4 hv = *(const float4*)(hcat + (size_t)row * 512 + tid * 4);
    *(float4*)(hrow + tid * 4) = hv;
    __syncthreads();

    float acc = fc1b[tid];
    const float* wrow = fc1w + (size_t)tid * 512;
#pragma unroll 4
    for (int k = 0; k < 512; k += 4) {
        float4 w = *(const float4*)(wrow + k);
        acc += w.x * hrow[k] + w.y * hrow[k + 1] + w.z * hrow[k + 2] + w.w * hrow[k + 3];
    }
    hid[tid] = fmaxf(acc, 0.f);
    __syncthreads();

    if (tid < 64) {
        float a2 = fc2b[tid];
        const float* w2 = fc2w + (size_t)tid * 128;
#pragma unroll 4
        for (int k = 0; k < 128; k += 4) {
            float4 w = *(const float4*)(w2 + k);
            a2 += w.x * hid[k] + w.y * hid[k + 1] + w.z * hid[k + 2] + w.w * hid[k + 3];
        }
        float ss = a2 * a2;
#pragma unroll
        for (int off = 32; off > 0; off >>= 1) ss += __shfl_down(ss, off);
        ss = __shfl(ss, 0);
        float scale = 1.f / fmaxf(sqrtf(ss), 1e-12f);
        out[(size_t)row * 64 + tid] = a2 * scale;
    }
}

// ---------------- launcher ----------------
// PATH A ws layout: wih(393216) | whh(786432) | hcat(524288) | xp(402653184)  => 404,357,120 B
// PATH B ws layout: emb(33554432) | wih | whh | hcat                          => ~35.3 MB
#define A_OFF_WIH  ((size_t)0)
#define A_OFF_WHH  ((size_t)393216)
#define A_OFF_HCAT ((size_t)(393216 + 786432))
#define A_OFF_XP   ((size_t)(393216 + 786432 + 524288))
#define A_TOTAL    ((size_t)(393216 + 786432 + 524288) + (size_t)402653184)

#define B_OFF_EMB  ((size_t)0)
#define B_OFF_WIH  ((size_t)33554432)
#define B_OFF_WHH  ((size_t)(33554432 + 393216))
#define B_OFF_HCAT ((size_t)(33554432 + 393216 + 786432))

extern "C" void kernel_launch(void* const* d_in, const int* in_sizes, int n_in,
                              void* d_out, int out_size, void* d_ws, size_t ws_size,
                              hipStream_t stream) {
    const int*   x      = (const int*)d_in[0];
    const int*   lens   = (const int*)d_in[1];
    const float* embedding = (const float*)d_in[2];
    const float* w_ih_f = (const float*)d_in[3];
    const float* w_hh_f = (const float*)d_in[4];
    const float* b_ih_f = (const float*)d_in[5];
    const float* b_hh_f = (const float*)d_in[6];
    const float* w_ih_b = (const float*)d_in[7];
    const float* w_hh_b = (const float*)d_in[8];
    const float* b_ih_b = (const float*)d_in[9];
    const float* b_hh_b = (const float*)d_in[10];
    const float* fc1_w  = (const float*)d_in[11];
    const float* fc1_b  = (const float*)d_in[12];
    const float* fc2_w  = (const float*)d_in[13];
    const float* fc2_b  = (const float*)d_in[14];
    float* out = (float*)d_out;

    char* ws = (char*)d_ws;

    if (ws_size >= A_TOTAL) {
        u16*   wih_bf = (u16*)(ws + A_OFF_WIH);
        u16*   whh_bf = (u16*)(ws + A_OFF_WHH);
        float* hcat   = (float*)(ws + A_OFF_HCAT);
        u16*   xp     = (u16*)(ws + A_OFF_XP);

        f32_to_bf16_kernel<<<192, 256, 0, stream>>>(w_ih_f, wih_bf, 49152);
        f32_to_bf16_kernel<<<192, 256, 0, stream>>>(w_ih_b, wih_bf + 98304, 49152);
        f32_to_bf16_kernel<<<384, 256, 0, stream>>>(w_hh_f, whh_bf, 98304);
        f32_to_bf16_kernel<<<384, 256, 0, stream>>>(w_hh_b, whh_bf + 196608, 98304);

        xp_gemm_kernel<<<4096, 512, 0, stream>>>(x, embedding, wih_bf,
                                                 b_ih_f, b_hh_f, b_ih_b, b_hh_b, xp);

        gru_xp_kernel<<<32, 512, 0, stream>>>(xp, whh_bf, b_hh_f, b_hh_b, lens, hcat);

        fc_head_kernel<<<256, 128, 0, stream>>>(hcat, fc1_w, fc1_b, fc2_w, fc2_b, out);
    } else {
        u16*   emb_bf = (u16*)(ws + B_OFF_EMB);
        u16*   wih_bf = (u16*)(ws + B_OFF_WIH);
        u16*   whh_bf = (u16*)(ws + B_OFF_WHH);
        float* hcat   = (float*)(ws + B_OFF_HCAT);

        f32_to_bf16_kernel<<<192, 256, 0, stream>>>(w_ih_f, wih_bf, 49152);
        f32_to_bf16_kernel<<<192, 256, 0, stream>>>(w_ih_b, wih_bf + 98304, 49152);
        f32_to_bf16_kernel<<<384, 256, 0, stream>>>(w_hh_f, whh_bf, 98304);
        f32_to_bf16_kernel<<<384, 256, 0, stream>>>(w_hh_b, whh_bf + 196608, 98304);

        gather_emb_kernel<<<32768, 256, 0, stream>>>(x, embedding, emb_bf);

        gru_stream_kernel<<<32, 512, 0, stream>>>(emb_bf, wih_bf, whh_bf,
                                                  b_ih_f, b_hh_f, b_ih_b, b_hh_b,
                                                  lens, hcat);

        fc_head_kernel<<<256, 128, 0, stream>>>(hcat, fc1_w, fc1_b, fc2_w, fc2_b, out);
    }
}

// Round 3
// 1732.275 us; speedup vs baseline: 2.6933x; 2.6933x over previous
//
#include <hip/hip_runtime.h>
#include <hip/hip_bf16.h>

#define B_ 256
#define T_ 512
#define E_ 128
#define H_ 256

typedef __attribute__((ext_vector_type(8))) short short8;
typedef __attribute__((ext_vector_type(4))) float f32x4;
typedef unsigned short u16;

#define MFMA_BF16(a, b, c) __builtin_amdgcn_mfma_f32_16x16x32_bf16((a), (b), (c), 0, 0, 0)

__device__ __forceinline__ u16 f2bf(float f) {
    union { float f; unsigned int u; } v; v.f = f;
    unsigned int u = v.u;
    unsigned int r = (u + 0x7fffu + ((u >> 16) & 1u)) >> 16;  // RNE
    return (u16)r;
}
__device__ __forceinline__ float bflo(unsigned int u) {
    union { unsigned int u; float f; } v; v.u = u << 16; return v.f;
}
__device__ __forceinline__ float bfhi(unsigned int u) {
    union { unsigned int u; float f; } v; v.u = u & 0xffff0000u; return v.f;
}
__device__ __forceinline__ f32x4 up2(uint2 p) {
    f32x4 r; r[0] = bflo(p.x); r[1] = bfhi(p.x); r[2] = bflo(p.y); r[3] = bfhi(p.y); return r;
}
__device__ __forceinline__ uint2 pk4(float a, float b, float c, float d) {
    uint2 o;
    o.x = (unsigned)f2bf(a) | ((unsigned)f2bf(b) << 16);
    o.y = (unsigned)f2bf(c) | ((unsigned)f2bf(d) << 16);
    return o;
}
__device__ __forceinline__ float sigm(float x) { return 1.f / (1.f + __expf(-x)); }

// ---------------- fp32 -> bf16 weight conversion ----------------
__global__ void f32_to_bf16_kernel(const float* __restrict__ src, u16* __restrict__ dst, int n2) {
    int i = blockIdx.x * blockDim.x + threadIdx.x;
    if (i < n2) {
        float2 v = ((const float2*)src)[i];
        ushort2 o; o.x = f2bf(v.x); o.y = f2bf(v.y);
        ((ushort2*)dst)[i] = o;
    }
}

// ---------------- xp chunk GEMM ----------------
// xp layout (bf16, packed as uint2 per lane): slot = dir*C + lt, then
//   [slot][btile16][gtile48][lane64] where lane(quad,nl) packs rr=0..3:
//   value = xp(gate row gt*16+quad*4+rr, batch b = btile*16+nl) at t(dir,lt).
// gates r,z (gt<32) have b_ih+b_hh folded; n-gate (gt>=32) has b_ih only.
#define XP_SLOT_U2 49152   // 16*48*64 uint2 per t-slot

__launch_bounds__(512, 1)
__global__ void xp_gemm_kernel(const int* __restrict__ x, const float* __restrict__ emb,
                               const u16* __restrict__ wih,
                               const float* __restrict__ bih_f, const float* __restrict__ bhh_f,
                               const float* __restrict__ bih_b, const float* __restrict__ bhh_b,
                               u16* __restrict__ xp, int C, int c0) {
    const int per_dir = C * 4;
    const int dir = (blockIdx.x >= per_dir) ? 1 : 0;
    const int mb  = blockIdx.x - dir * per_dir;
    const int lt  = mb >> 2;
    const int b0  = (mb & 3) << 6;          // 64 batch rows per block
    const int t   = dir ? (T_ - 1 - (c0 + lt)) : (c0 + lt);
    const int tid  = threadIdx.x;
    const int wv   = tid >> 6;
    const int lane = tid & 63;
    const int nl   = lane & 15;
    const int quad = lane >> 4;

    __shared__ u16 A[64][136];

    const u16*   wih_d = wih + (size_t)dir * (768 * 128);
    const float* bih   = dir ? bih_b : bih_f;
    const float* bhh   = dir ? bhh_b : bhh_f;

    // w_ih fragments (A-operand): wave wv owns gtiles wv*6 .. wv*6+5
    short8 wfrag[6][4];
#pragma unroll
    for (int j = 0; j < 6; j++) {
        int gt = wv * 6 + j;
        const u16* p = wih_d + (size_t)(gt * 16 + nl) * 128 + quad * 8;
#pragma unroll
        for (int kt = 0; kt < 4; kt++) wfrag[j][kt] = *(const short8*)(p + kt * 32);
    }

    // stage embedding tile (64 rows x 128 cols) as bf16
#pragma unroll
    for (int i = 0; i < 4; i++) {
        int idx = tid + i * 512;
        int r = idx >> 5, c = idx & 31;
        int tok = x[(b0 + r) * T_ + t];
        float4 v = *(const float4*)(emb + (size_t)tok * E_ + c * 4);
        *(uint2*)&A[r][c * 4] = pk4(v.x, v.y, v.z, v.w);
    }
    __syncthreads();

    f32x4 acc[6][4];
#pragma unroll
    for (int j = 0; j < 6; j++)
#pragma unroll
        for (int mi = 0; mi < 4; mi++) acc[j][mi] = (f32x4){0, 0, 0, 0};

#pragma unroll
    for (int kt = 0; kt < 4; kt++) {
        short8 a[4];
#pragma unroll
        for (int mi = 0; mi < 4; mi++)
            a[mi] = *(const short8*)&A[mi * 16 + nl][quad * 8 + kt * 32];
#pragma unroll
        for (int j = 0; j < 6; j++)
#pragma unroll
            for (int mi = 0; mi < 4; mi++)
                acc[j][mi] = MFMA_BF16(wfrag[j][kt], a[mi], acc[j][mi]);  // w=A, emb=B
    }

    // epilogue: D[row=quad*4+rr = gate row in tile][col=nl = batch row]
    const int slot = dir * C + lt;
#pragma unroll
    for (int j = 0; j < 6; j++) {
        int gt = wv * 6 + j;
        int gate = gt >> 4;
        const float4 bi = *(const float4*)(bih + gt * 16 + quad * 4);
        const float4 bh = *(const float4*)(bhh + gt * 16 + quad * 4);
        float bb[4];
        bb[0] = bi.x + (gate < 2 ? bh.x : 0.f);
        bb[1] = bi.y + (gate < 2 ? bh.y : 0.f);
        bb[2] = bi.z + (gate < 2 ? bh.z : 0.f);
        bb[3] = bi.w + (gate < 2 ? bh.w : 0.f);
#pragma unroll
        for (int mi = 0; mi < 4; mi++) {
            int btile = ((mb & 3) << 2) + mi;
            f32x4 v = acc[j][mi];
            size_t base = (((size_t)slot * 16 + btile) * 48 + gt) * 64 + lane;
            ((uint2*)xp)[base] = pk4(v[0] + bb[0], v[1] + bb[1], v[2] + bb[2], v[3] + bb[3]);
        }
    }
}

// ---------------- GRU chunk recurrence ----------------
// 32 blocks (dir x 16 btiles), 512 thr = 8 waves, 2 waves/SIMD.
// Wave wv owns units [wv*32, wv*32+32). Lane(quad,nl): batch row b_base+nl,
// units wv*32+16*hh+quad*4+rr. w_hh fragment sets (A-operand):
//   regs: (r,h0)(r,h1)(z,h0)(z,h1)(n,h0); LDS (pre-swizzled linear): (n,h1).
// h mirror in LDS is fragment-linear: entry(kt,lane) = h[batch=lane&15]
// [units (lane>>4)*8 + kt*32 ..+8] -> stride-1 conflict-free b128 reads.
__launch_bounds__(512, 1)
__global__ void gru_chunk_kernel(const u16* __restrict__ xp, const u16* __restrict__ whh,
                                 const float* __restrict__ bhh_f, const float* __restrict__ bhh_b,
                                 const int* __restrict__ lengths,
                                 float* __restrict__ hstate,   // [dir][256][256] f32
                                 int C, int c0) {
    const int dir    = blockIdx.x >> 4;
    const int btile  = blockIdx.x & 15;
    const int b_base = btile << 4;
    const int wv     = threadIdx.x >> 6;
    const int lane   = threadIdx.x & 63;
    const int nl     = lane & 15;
    const int quad   = lane >> 4;

    __shared__ u16 hfr[2][4096];     // 2 x 8KB h mirrors, fragment-linear
    __shared__ u16 wn[32768];        // 64KB: (n-gate,h1) set, fragment-linear

    const u16*   whh_d = whh + (size_t)dir * (768 * 256);
    const float* bhh   = dir ? bhh_b : bhh_f;

    // stage wn: entry e=(wv_e,kt_e,lane_e): whh row 512+wv_e*32+16+(lane_e&15),
    // cols (lane_e>>4)*8 + kt_e*32
    for (int e = threadIdx.x; e < 4096; e += 512) {
        int wv_e = e >> 9, kt_e = (e >> 6) & 7, ln_e = e & 63;
        const u16* src = whh_d + (size_t)(512 + wv_e * 32 + 16 + (ln_e & 15)) * 256
                       + (ln_e >> 4) * 8 + kt_e * 32;
        *(short8*)&wn[e * 8] = *(const short8*)src;
    }

    // register w_hh fragment sets: rows (gate base + wv*32 + 16*hh + nl)
    short8 w[5][8];
    {
        const int row[5] = {wv * 32 + nl, wv * 32 + 16 + nl,
                            256 + wv * 32 + nl, 256 + wv * 32 + 16 + nl,
                            512 + wv * 32 + nl};
#pragma unroll
        for (int gh = 0; gh < 5; gh++) {
            const u16* p = whh_d + (size_t)row[gh] * 256 + quad * 8;
#pragma unroll
            for (int kt = 0; kt < 8; kt++) w[gh][kt] = *(const short8*)(p + kt * 32);
        }
    }

    const float4 bnh0 = *(const float4*)(bhh + 512 + wv * 32 + quad * 4);
    const float4 bnh1 = *(const float4*)(bhh + 512 + wv * 32 + 16 + quad * 4);
    const int len = lengths[b_base + nl];

    // h master copy (fp32) + initial mirror write
    float hreg[2][4];
    const int o0 = quad * 4, o1 = 16 + quad * 4;
    const int widx0 = (wv * 64 + (o0 >> 3) * 16 + nl) * 8 + (o0 & 7);
    const int widx1 = (wv * 64 + (o1 >> 3) * 16 + nl) * 8 + (o1 & 7);
    if (c0 == 0) {
#pragma unroll
        for (int hh = 0; hh < 2; hh++)
#pragma unroll
            for (int rr = 0; rr < 4; rr++) hreg[hh][rr] = 0.f;
    } else {
        const float* hs = hstate + ((size_t)(dir * 256 + b_base + nl)) * 256 + wv * 32;
        float4 h0 = *(const float4*)(hs + o0);
        float4 h1 = *(const float4*)(hs + o1);
        hreg[0][0] = h0.x; hreg[0][1] = h0.y; hreg[0][2] = h0.z; hreg[0][3] = h0.w;
        hreg[1][0] = h1.x; hreg[1][1] = h1.y; hreg[1][2] = h1.z; hreg[1][3] = h1.w;
    }
    *(uint2*)&hfr[0][widx0] = pk4(hreg[0][0], hreg[0][1], hreg[0][2], hreg[0][3]);
    *(uint2*)&hfr[0][widx1] = pk4(hreg[1][0], hreg[1][1], hreg[1][2], hreg[1][3]);

    // xp pointers (slot-linear, always forward in local step)
    const uint2* pg0;
    const uint2* pg1;
    const uint2* pg2;
    {
        size_t base = (((size_t)(dir * C) * 16 + btile) * 48) * 64 + lane;
        pg0 = (const uint2*)xp + base + (0 * 16 + wv * 2) * 64;
        pg1 = (const uint2*)xp + base + (1 * 16 + wv * 2) * 64;
        pg2 = (const uint2*)xp + base + (2 * 16 + wv * 2) * 64;
    }
    uint2 pf0[2], pf1[2], pf2[2];
    pf0[0] = pg0[0]; pf0[1] = pg0[64];
    pf1[0] = pg1[0]; pf1[1] = pg1[64];
    pf2[0] = pg2[0]; pf2[1] = pg2[64];

    __syncthreads();

    for (int ls = 0; ls < C; ls++) {
        const int s = c0 + ls;
        const int t = dir ? (T_ - 1 - s) : s;
        const int cur = ls & 1, nxt = cur ^ 1;

        f32x4 accr[2], accz[2], accn[2], xpn[2];
        accr[0] = up2(pf0[0]); accr[1] = up2(pf0[1]);
        accz[0] = up2(pf1[0]); accz[1] = up2(pf1[1]);
        xpn[0]  = up2(pf2[0]); xpn[1]  = up2(pf2[1]);
        accn[0] = (f32x4){bnh0.x, bnh0.y, bnh0.z, bnh0.w};
        accn[1] = (f32x4){bnh1.x, bnh1.y, bnh1.z, bnh1.w};

        // prefetch next local step (ls=C lands in next-dir slot or the pad slot)
        pg0 += XP_SLOT_U2; pg1 += XP_SLOT_U2; pg2 += XP_SLOT_U2;
        pf0[0] = pg0[0]; pf0[1] = pg0[64];
        pf1[0] = pg1[0]; pf1[1] = pg1[64];
        pf2[0] = pg2[0]; pf2[1] = pg2[64];

#pragma unroll
        for (int kt = 0; kt < 8; kt++) {
            short8 hv = *(const short8*)&hfr[cur][(kt * 64 + lane) * 8];
            accr[0] = MFMA_BF16(w[0][kt], hv, accr[0]);
            accr[1] = MFMA_BF16(w[1][kt], hv, accr[1]);
            accz[0] = MFMA_BF16(w[2][kt], hv, accz[0]);
            accz[1] = MFMA_BF16(w[3][kt], hv, accz[1]);
            accn[0] = MFMA_BF16(w[4][kt], hv, accn[0]);
            short8 bn = *(const short8*)&wn[((wv * 8 + kt) * 64 + lane) * 8];
            accn[1] = MFMA_BF16(bn, hv, accn[1]);
        }

        const bool upd = (t < len);
#pragma unroll
        for (int hh = 0; hh < 2; hh++) {
#pragma unroll
            for (int rr = 0; rr < 4; rr++) {
                float r = sigm(accr[hh][rr]);
                float z = sigm(accz[hh][rr]);
                float npre = xpn[hh][rr] + r * accn[hh][rr];
                float nn = 1.f - 2.f / (1.f + __expf(2.f * npre));
                float hn = nn + z * (hreg[hh][rr] - nn);
                if (upd) hreg[hh][rr] = hn;
            }
        }
        *(uint2*)&hfr[nxt][widx0] = pk4(hreg[0][0], hreg[0][1], hreg[0][2], hreg[0][3]);
        *(uint2*)&hfr[nxt][widx1] = pk4(hreg[1][0], hreg[1][1], hreg[1][2], hreg[1][3]);
        __syncthreads();
    }

    // carry h out (coalesced float4)
    float* hs = hstate + ((size_t)(dir * 256 + b_base + nl)) * 256 + wv * 32;
    *(float4*)(hs + o0) = (float4){hreg[0][0], hreg[0][1], hreg[0][2], hreg[0][3]};
    *(float4*)(hs + o1) = (float4){hreg[1][0], hreg[1][1], hreg[1][2], hreg[1][3]};
}

// ---------------- FC head + row L2-normalize ----------------
__global__ void fc_head_kernel(const float* __restrict__ hstate,
                               const float* __restrict__ fc1w, const float* __restrict__ fc1b,
                               const float* __restrict__ fc2w, const float* __restrict__ fc2b,
                               float* __restrict__ out) {
    int row = blockIdx.x;
    int tid = threadIdx.x;  // 128
    __shared__ float hrow[512];
    __shared__ float hid[128];

    // k = dir*256 + u ; hstate[(dir*256+row)*256 + u]
    {
        int dir = tid >> 6, u = (tid & 63) * 4;
        float4 hv = *(const float4*)(hstate + ((size_t)(dir * 256 + row)) * 256 + u);
        *(float4*)(hrow + tid * 4) = hv;
    }
    __syncthreads();

    float acc = fc1b[tid];
    const float* wrow = fc1w + (size_t)tid * 512;
#pragma unroll 4
    for (int k = 0; k < 512; k += 4) {
        float4 w = *(const float4*)(wrow + k);
        acc += w.x * hrow[k] + w.y * hrow[k + 1] + w.z * hrow[k + 2] + w.w * hrow[k + 3];
    }
    hid[tid] = fmaxf(acc, 0.f);
    __syncthreads();

    if (tid < 64) {
        float a2 = fc2b[tid];
        const float* w2 = fc2w + (size_t)tid * 128;
#pragma unroll 4
        for (int k = 0; k < 128; k += 4) {
            float4 w = *(const float4*)(w2 + k);
            a2 += w.x * hid[k] + w.y * hid[k + 1] + w.z * hid[k + 2] + w.w * hid[k + 3];
        }
        float ss = a2 * a2;
#pragma unroll
        for (int off = 32; off > 0; off >>= 1) ss += __shfl_down(ss, off);
        ss = __shfl(ss, 0);
        float scale = 1.f / fmaxf(sqrtf(ss), 1e-12f);
        out[(size_t)row * 64 + tid] = a2 * scale;
    }
}

// ---------------- launcher ----------------
// ws: wih(393216) | whh(786432) | hstate(524288) | xp chunk ((2C+1)*393216)
// C=32 total = 27.26 MB  (proven ws >= 35.3 MB from R0/R1's Path B)
#define OFF_WIH  ((size_t)0)
#define OFF_WHH  ((size_t)393216)
#define OFF_HST  ((size_t)(393216 + 786432))
#define OFF_XP   ((size_t)(393216 + 786432 + 524288))
#define SLOT_B   ((size_t)393216)

extern "C" void kernel_launch(void* const* d_in, const int* in_sizes, int n_in,
                              void* d_out, int out_size, void* d_ws, size_t ws_size,
                              hipStream_t stream) {
    const int*   x      = (const int*)d_in[0];
    const int*   lens   = (const int*)d_in[1];
    const float* embedding = (const float*)d_in[2];
    const float* w_ih_f = (const float*)d_in[3];
    const float* w_hh_f = (const float*)d_in[4];
    const float* b_ih_f = (const float*)d_in[5];
    const float* b_hh_f = (const float*)d_in[6];
    const float* w_ih_b = (const float*)d_in[7];
    const float* w_hh_b = (const float*)d_in[8];
    const float* b_ih_b = (const float*)d_in[9];
    const float* b_hh_b = (const float*)d_in[10];
    const float* fc1_w  = (const float*)d_in[11];
    const float* fc1_b  = (const float*)d_in[12];
    const float* fc2_w  = (const float*)d_in[13];
    const float* fc2_b  = (const float*)d_in[14];
    float* out = (float*)d_out;

    char* ws = (char*)d_ws;
    u16*   wih_bf = (u16*)(ws + OFF_WIH);
    u16*   whh_bf = (u16*)(ws + OFF_WHH);
    float* hstate = (float*)(ws + OFF_HST);
    u16*   xp     = (u16*)(ws + OFF_XP);

    // largest chunk size whose xp buffer fits the workspace (ws_size is constant
    // across calls, so this branch is graph-stable)
    int C = 32;
    if      (ws_size >= OFF_XP + (size_t)(2 * 512 + 1) * SLOT_B) C = 512;
    else if (ws_size >= OFF_XP + (size_t)(2 * 256 + 1) * SLOT_B) C = 256;
    else if (ws_size >= OFF_XP + (size_t)(2 * 128 + 1) * SLOT_B) C = 128;
    else if (ws_size >= OFF_XP + (size_t)(2 * 64  + 1) * SLOT_B) C = 64;

    f32_to_bf16_kernel<<<192, 256, 0, stream>>>(w_ih_f, wih_bf, 49152);
    f32_to_bf16_kernel<<<192, 256, 0, stream>>>(w_ih_b, wih_bf + 98304, 49152);
    f32_to_bf16_kernel<<<384, 256, 0, stream>>>(w_hh_f, whh_bf, 98304);
    f32_to_bf16_kernel<<<384, 256, 0, stream>>>(w_hh_b, whh_bf + 196608, 98304);

    const int nchunks = T_ / C;
    for (int c = 0; c < nchunks; c++) {
        xp_gemm_kernel<<<8 * C, 512, 0, stream>>>(x, embedding, wih_bf,
                                                  b_ih_f, b_hh_f, b_ih_b, b_hh_b,
                                                  xp, C, c * C);
        gru_chunk_kernel<<<32, 512, 0, stream>>>(xp, whh_bf, b_hh_f, b_hh_b,
                                                 lens, hstate, C, c * C);
    }

    fc_head_kernel<<<256, 128, 0, stream>>>(hstate, fc1_w, fc1_b, fc2_w, fc2_b, out);
}